// Round 7
// baseline (95.835 us; speedup 1.0000x reference)
//
#include <hip/hip_runtime.h>
#include <math.h>

#define N_EDGES   1000000
#define N_NODES   100000
#define THR_LO    0.6f
#define THR_HI    0.8f
#define LOG_CLAMP -100.0f

#define NBLOCKS   2048
#define BLOCK     256

// d_ws layout:
//   0x00000: float4 part[NBLOCKS]      32 KB  (block partials; written unconditionally)
//   0x08000: uint   cls[N_NODES/16]    25 KB  (2-bit node codes, 16/word)
//   0x10000: uchar  qfeats[N_NODES*64] 6.4 MB (fp8 e4m3 feats, row = 64 B)
#define CLS_OFF   0x8000
#define QF_OFF    0x10000

#if defined(__has_builtin)
#if __has_builtin(__builtin_amdgcn_cvt_pk_fp8_f32) && __has_builtin(__builtin_amdgcn_cvt_pk_f32_fp8)
#define HAVE_FP8_CVT 1
#endif
#endif

typedef float v2f __attribute__((ext_vector_type(2)));

// ---------------- fp8 e4m3 encode (RNE) ----------------
__device__ __forceinline__ unsigned f32_to_fp8_sw(float f) {
    unsigned u = __float_as_uint(f);
    unsigned s = (u >> 24) & 0x80u;
    float a = fabsf(f);
    if (a >= 448.f) return s | 0x7Eu;               // clamp to max normal
    unsigned au = u & 0x7FFFFFFFu;
    int E = (int)(au >> 23) - 127;
    if (E >= -6) {                                   // normal in fp8
        unsigned m   = au & 0x7FFFFFu;
        unsigned keep = m >> 20;
        unsigned rem  = m & 0xFFFFFu;
        keep += (rem > 0x80000u) || (rem == 0x80000u && (keep & 1u));
        unsigned val = (((unsigned)(E + 7)) << 3) + keep;  // carry rolls into exp
        return s | val;
    } else {                                         // denormal (granule 2^-9)
        float q = a * 512.0f;                        // < 8
        unsigned k = (unsigned)(q + 0.5f);           // k==8 -> 0x08 == 2^-6, continuous
        return s | k;
    }
}

__device__ __forceinline__ unsigned pack4_fp8(float4 v) {
#if HAVE_FP8_CVT
    int w = 0;
    w = __builtin_amdgcn_cvt_pk_fp8_f32(v.x, v.y, w, false);  // bytes 0,1
    w = __builtin_amdgcn_cvt_pk_fp8_f32(v.z, v.w, w, true);   // bytes 2,3
    return (unsigned)w;
#else
    return f32_to_fp8_sw(v.x) | (f32_to_fp8_sw(v.y) << 8) |
           (f32_to_fp8_sw(v.z) << 16) | (f32_to_fp8_sw(v.w) << 24);
#endif
}

// ---------------- fp8 e4m3 decode + diff-square ----------------
__device__ __forceinline__ float fp8_to_f32_sw(unsigned byte) {
    unsigned s  = (byte & 0x80u) << 24;
    unsigned em = (byte & 0x7Fu) << 20;
    return __uint_as_float(s | em) * 0x1p+120f;      // exp rebias 7 -> 127
}

__device__ __forceinline__ float sq8(unsigned a, unsigned b) {
#if HAVE_FP8_CVT
    v2f a0 = __builtin_amdgcn_cvt_pk_f32_fp8((int)a, false);
    v2f a1 = __builtin_amdgcn_cvt_pk_f32_fp8((int)a, true);
    v2f b0 = __builtin_amdgcn_cvt_pk_f32_fp8((int)b, false);
    v2f b1 = __builtin_amdgcn_cvt_pk_f32_fp8((int)b, true);
    float d0 = a0.x - b0.x, d1 = a0.y - b0.y;
    float d2 = a1.x - b1.x, d3 = a1.y - b1.y;
#else
    float d0 = fp8_to_f32_sw(a & 255u)         - fp8_to_f32_sw(b & 255u);
    float d1 = fp8_to_f32_sw((a >> 8) & 255u)  - fp8_to_f32_sw((b >> 8) & 255u);
    float d2 = fp8_to_f32_sw((a >> 16) & 255u) - fp8_to_f32_sw((b >> 16) & 255u);
    float d3 = fp8_to_f32_sw(a >> 24)          - fp8_to_f32_sw(b >> 24);
#endif
    return d0 * d0 + d1 * d1 + d2 * d2 + d3 * d3;
}

__device__ __forceinline__ float sq16(uint4 A, uint4 B) {
    return sq8(A.x, B.x) + sq8(A.y, B.y) + sq8(A.z, B.z) + sq8(A.w, B.w);
}

__device__ __forceinline__ void accum_edge(float s, int simflag,
                                           float& sim, float& dis) {
    float d = sqrtf(s);
    if (simflag) {
        sim += fminf(d, 100.0f);                     // -max(log(exp(-d)),-100)
    } else {
        float p = expf(-d);
        dis += -fmaxf(log1pf(-p), LOG_CLAMP);
    }
}

// ---------------- prep: fp8 convert + 2-bit classify ----------------
__global__ void __launch_bounds__(BLOCK)
prep_kernel(const float* __restrict__ probas,
            const float4* __restrict__ feats,        // N_NODES*16 float4
            unsigned* __restrict__ cls,
            unsigned* __restrict__ qf) {             // N_NODES*16 uint (4 fp8 each)
    int t = blockIdx.x * blockDim.x + threadIdx.x;
    const int NF4 = N_NODES * 16;
    if (t < NF4) {
        qf[t] = pack4_fp8(feats[t]);
    }
    if (t < N_NODES / 16) {                          // 6250 words, 16 nodes each
        unsigned w = 0;
        #pragma unroll
        for (int k = 0; k < 16; ++k) {
            float p = probas[t * 16 + k];
            unsigned c = (p >= THR_HI ? 1u : 0u) | (p < THR_LO ? 2u : 0u);
            w |= c << (2 * k);
        }
        cls[t] = w;
    }
}

// ---------------- main: mask + compact + coalesced fp8 gathers ----------------
__global__ void __launch_bounds__(BLOCK)
edge_loss_kernel(const int2* __restrict__ edges,
                 const unsigned* __restrict__ cls,
                 const uint4* __restrict__ qfeat,    // N_NODES rows of 4 uint4 (64 B)
                 float4* __restrict__ part) {
    const int lane = threadIdx.x & 63;
    const int wave = threadIdx.x >> 6;
    const int grp  = lane >> 2;                      // 16 groups of 4 lanes
    const int sub  = lane & 3;

    __shared__ int sh_i[4][64];
    __shared__ int sh_j[4][64];

    float sim = 0.f, dis = 0.f, ns = 0.f, nd = 0.f;

    const int gstride = gridDim.x * blockDim.x;
    for (int base = blockIdx.x * blockDim.x; base < N_EDGES; base += gstride) {
        // ---- mask phase: 1 edge per lane; 25 KB cls table is L1/L2-resident
        int e = base + threadIdx.x;
        bool in = (e < N_EDGES);
        int2 ij = in ? edges[e] : make_int2(0, 0);
        unsigned ci = (cls[ij.x >> 4] >> ((ij.x & 15) * 2)) & 3u;
        unsigned cj = (cls[ij.y >> 4] >> ((ij.y & 15) * 2)) & 3u;
        bool msim = in && ((ci & cj & 1u) != 0u);
        bool mdis = in && ((((ci & 1u) & (cj >> 1)) | ((cj & 1u) & (ci >> 1))) != 0u);

        unsigned long long balsim = __ballot(msim);
        unsigned long long baldis = __ballot(mdis);
        unsigned long long m      = balsim | baldis;
        if (lane == 0) {
            ns += (float)__popcll(balsim);
            nd += (float)__popcll(baldis);
        }
        int count = __popcll(m);

        if (msim | mdis) {
            int prefix = __popcll(m & ((1ULL << lane) - 1ULL));
            sh_i[wave][prefix] = ij.x | (msim ? (int)0x80000000 : 0);
            sh_j[wave][prefix] = ij.y;
        }
        __syncthreads();

        // ---- cooperative phase: 4 lanes/edge, 2 edges deep, fp8 rows (64 B)
        for (int t = grp; t < count; t += 32) {
            bool h2 = (t + 16) < count;
            int  tb = h2 ? t + 16 : t;

            int xa_i = sh_i[wave][t],  xa_j = sh_j[wave][t];
            int xb_i = sh_i[wave][tb], xb_j = sh_j[wave][tb];

            const uint4* rai = qfeat + (size_t)(xa_i & 0x7FFFFFFF) * 4;
            const uint4* raj = qfeat + (size_t)xa_j * 4;
            const uint4* rbi = qfeat + (size_t)(xb_i & 0x7FFFFFFF) * 4;
            const uint4* rbj = qfeat + (size_t)xb_j * 4;

            // 4 independent 16B loads in flight per lane; group covers a 64B row
            uint4 A = rai[sub];
            uint4 B = raj[sub];
            uint4 C = rbi[sub];
            uint4 D = rbj[sub];

            float s1 = sq16(A, B);
            float s2 = sq16(C, D);

            s1 += __shfl_xor(s1, 1); s1 += __shfl_xor(s1, 2);
            s2 += __shfl_xor(s2, 1); s2 += __shfl_xor(s2, 2);

            if (sub == 0) {
                accum_edge(s1, ((unsigned)xa_i) >> 31, sim, dis);
                if (h2) accum_edge(s2, ((unsigned)xb_i) >> 31, sim, dis);
            }
        }
        __syncthreads();
    }

    // ---- block reduction (plain store, no global atomics) ----
    #pragma unroll
    for (int off = 32; off > 0; off >>= 1) {
        sim += __shfl_down(sim, off);
        dis += __shfl_down(dis, off);
        ns  += __shfl_down(ns,  off);
        nd  += __shfl_down(nd,  off);
    }
    __shared__ float lds[4][4];
    if (lane == 0) {
        lds[wave][0] = sim; lds[wave][1] = dis;
        lds[wave][2] = ns;  lds[wave][3] = nd;
    }
    __syncthreads();
    if (threadIdx.x == 0) {
        float a = 0.f, b = 0.f, c = 0.f, d4 = 0.f;
        #pragma unroll
        for (int w = 0; w < 4; ++w) {
            a += lds[w][0]; b += lds[w][1]; c += lds[w][2]; d4 += lds[w][3];
        }
        part[blockIdx.x] = make_float4(a, b, c, d4);
    }
}

__global__ void __launch_bounds__(BLOCK)
finalize_kernel(const float4* __restrict__ part,
                float* __restrict__ out) {
    float a = 0.f, b = 0.f, c = 0.f, d4 = 0.f;
    for (int i = threadIdx.x; i < NBLOCKS; i += BLOCK) {
        float4 p = part[i];
        a += p.x; b += p.y; c += p.z; d4 += p.w;
    }
    #pragma unroll
    for (int off = 32; off > 0; off >>= 1) {
        a  += __shfl_down(a,  off);
        b  += __shfl_down(b,  off);
        c  += __shfl_down(c,  off);
        d4 += __shfl_down(d4, off);
    }
    __shared__ float lds[4][4];
    int lane = threadIdx.x & 63;
    int wave = threadIdx.x >> 6;
    if (lane == 0) {
        lds[wave][0] = a; lds[wave][1] = b; lds[wave][2] = c; lds[wave][3] = d4;
    }
    __syncthreads();
    if (threadIdx.x == 0) {
        float sim_sum = 0.f, disim_sum = 0.f, n_sim = 0.f, n_disim = 0.f;
        #pragma unroll
        for (int w = 0; w < 4; ++w) {
            sim_sum   += lds[w][0];
            disim_sum += lds[w][1];
            n_sim     += lds[w][2];
            n_disim   += lds[w][3];
        }
        float total = n_sim + n_disim;
        out[0] = (sim_sum * (n_disim / total) +
                  disim_sum * (n_sim / total)) / total;
    }
}

extern "C" void kernel_launch(void* const* d_in, const int* in_sizes, int n_in,
                              void* d_out, int out_size, void* d_ws, size_t ws_size,
                              hipStream_t stream) {
    const int*   edges  = (const int*)d_in[0];    // (N_EDGES, 2) int32
    const float* probas = (const float*)d_in[1];  // (N_NODES,)
    const float* feats  = (const float*)d_in[2];  // (N_NODES, 64) fp32

    float4*   part = (float4*)d_ws;
    unsigned* cls  = (unsigned*)((char*)d_ws + CLS_OFF);
    unsigned* qf   = (unsigned*)((char*)d_ws + QF_OFF);

    const int NF4 = N_NODES * 16;                 // 1.6M float4 -> uint conversions
    prep_kernel<<<(NF4 + BLOCK - 1) / BLOCK, BLOCK, 0, stream>>>(
        probas, (const float4*)feats, cls, qf);

    edge_loss_kernel<<<NBLOCKS, BLOCK, 0, stream>>>(
        (const int2*)edges, cls, (const uint4*)qf, part);

    finalize_kernel<<<1, BLOCK, 0, stream>>>(part, (float*)d_out);
}

// Round 8
// 94.904 us; speedup vs baseline: 1.0098x; 1.0098x over previous
//
#include <hip/hip_runtime.h>
#include <math.h>

#define N_EDGES   1000000
#define N_NODES   100000
#define THR_LO    0.6f
#define THR_HI    0.8f
#define LOG_CLAMP -100.0f

#define BLOCK     256
#define NBLK      ((N_EDGES + BLOCK - 1) / BLOCK)   // 3907, one edge per thread

// d_ws layout:
//   0x00000: float4 part[NBLK]        62.5 KB (block partials; written unconditionally)
//   0x10000: uint   cls[N_NODES/16]   25 KB   (2-bit node codes, 16/word)
//   0x18000: uchar  qfeats[N_NODES*64] 6.4 MB (fp8 e4m3 feats, row = 64 B)
#define CLS_OFF   0x10000
#define QF_OFF    0x18000

#if defined(__has_builtin)
#if __has_builtin(__builtin_amdgcn_cvt_pk_fp8_f32) && __has_builtin(__builtin_amdgcn_cvt_pk_f32_fp8)
#define HAVE_FP8_CVT 1
#endif
#endif

typedef float v2f __attribute__((ext_vector_type(2)));

// ---------------- fp8 e4m3 encode (RNE) ----------------
__device__ __forceinline__ unsigned f32_to_fp8_sw(float f) {
    unsigned u = __float_as_uint(f);
    unsigned s = (u >> 24) & 0x80u;
    float a = fabsf(f);
    if (a >= 448.f) return s | 0x7Eu;
    unsigned au = u & 0x7FFFFFFFu;
    int E = (int)(au >> 23) - 127;
    if (E >= -6) {
        unsigned m    = au & 0x7FFFFFu;
        unsigned keep = m >> 20;
        unsigned rem  = m & 0xFFFFFu;
        keep += (rem > 0x80000u) || (rem == 0x80000u && (keep & 1u));
        unsigned val = (((unsigned)(E + 7)) << 3) + keep;
        return s | val;
    } else {
        float q = a * 512.0f;
        unsigned k = (unsigned)(q + 0.5f);
        return s | k;
    }
}

__device__ __forceinline__ unsigned pack4_fp8(float4 v) {
#if HAVE_FP8_CVT
    int w = 0;
    w = __builtin_amdgcn_cvt_pk_fp8_f32(v.x, v.y, w, false);
    w = __builtin_amdgcn_cvt_pk_fp8_f32(v.z, v.w, w, true);
    return (unsigned)w;
#else
    return f32_to_fp8_sw(v.x) | (f32_to_fp8_sw(v.y) << 8) |
           (f32_to_fp8_sw(v.z) << 16) | (f32_to_fp8_sw(v.w) << 24);
#endif
}

// ---------------- fp8 e4m3 decode + diff-square ----------------
__device__ __forceinline__ float fp8_to_f32_sw(unsigned byte) {
    unsigned s  = (byte & 0x80u) << 24;
    unsigned em = (byte & 0x7Fu) << 20;
    return __uint_as_float(s | em) * 0x1p+120f;
}

__device__ __forceinline__ float sq8(unsigned a, unsigned b) {
#if HAVE_FP8_CVT
    v2f a0 = __builtin_amdgcn_cvt_pk_f32_fp8((int)a, false);
    v2f a1 = __builtin_amdgcn_cvt_pk_f32_fp8((int)a, true);
    v2f b0 = __builtin_amdgcn_cvt_pk_f32_fp8((int)b, false);
    v2f b1 = __builtin_amdgcn_cvt_pk_f32_fp8((int)b, true);
    float d0 = a0.x - b0.x, d1 = a0.y - b0.y;
    float d2 = a1.x - b1.x, d3 = a1.y - b1.y;
#else
    float d0 = fp8_to_f32_sw(a & 255u)         - fp8_to_f32_sw(b & 255u);
    float d1 = fp8_to_f32_sw((a >> 8) & 255u)  - fp8_to_f32_sw((b >> 8) & 255u);
    float d2 = fp8_to_f32_sw((a >> 16) & 255u) - fp8_to_f32_sw((b >> 16) & 255u);
    float d3 = fp8_to_f32_sw(a >> 24)          - fp8_to_f32_sw(b >> 24);
#endif
    return d0 * d0 + d1 * d1 + d2 * d2 + d3 * d3;
}

__device__ __forceinline__ float sq16(uint4 A, uint4 B) {
    return sq8(A.x, B.x) + sq8(A.y, B.y) + sq8(A.z, B.z) + sq8(A.w, B.w);
}

__device__ __forceinline__ void accum_edge(float s, int simflag,
                                           float& sim, float& dis) {
    float d = sqrtf(s);
    if (simflag) {
        sim += fminf(d, 100.0f);                 // -max(log(exp(-d)),-100)
    } else {
        float p = expf(-d);
        dis += -fmaxf(log1pf(-p), LOG_CLAMP);
    }
}

// ---------------- prep: fp8 convert + 2-bit classify ----------------
__global__ void __launch_bounds__(BLOCK)
prep_kernel(const float* __restrict__ probas,
            const float4* __restrict__ feats,
            unsigned* __restrict__ cls,
            unsigned* __restrict__ qf) {
    int t = blockIdx.x * blockDim.x + threadIdx.x;
    const int NF4 = N_NODES * 16;
    if (t < NF4) {
        qf[t] = pack4_fp8(feats[t]);
    }
    if (t < N_NODES / 16) {
        unsigned w = 0;
        #pragma unroll
        for (int k = 0; k < 16; ++k) {
            float p = probas[t * 16 + k];
            unsigned c = (p >= THR_HI ? 1u : 0u) | (p < THR_LO ? 2u : 0u);
            w |= c << (2 * k);
        }
        cls[t] = w;
    }
}

// ------- main: one edge/thread, block-level compact, balanced gather -------
__global__ void __launch_bounds__(BLOCK)
edge_loss_kernel(const int2* __restrict__ edges,
                 const unsigned* __restrict__ cls,
                 const uint4* __restrict__ qfeat,   // N_NODES rows of 4 uint4 (64 B)
                 float4* __restrict__ part) {
    const int lane = threadIdx.x & 63;
    const int wave = threadIdx.x >> 6;
    const int g    = threadIdx.x >> 2;              // 64 groups of 4 lanes
    const int sub  = threadIdx.x & 3;

    __shared__ int sh_i[BLOCK];
    __shared__ int sh_j[BLOCK];
    __shared__ unsigned wcnt[4];

    float sim = 0.f, dis = 0.f, ns = 0.f, nd = 0.f;

    // ---- mask phase: 1 edge per thread, single pass ----
    int e = blockIdx.x * BLOCK + threadIdx.x;
    bool in = (e < N_EDGES);
    int2 ij = in ? edges[e] : make_int2(0, 0);
    unsigned ci = (cls[ij.x >> 4] >> ((ij.x & 15) * 2)) & 3u;
    unsigned cj = (cls[ij.y >> 4] >> ((ij.y & 15) * 2)) & 3u;
    bool msim = in && ((ci & cj & 1u) != 0u);
    bool mdis = in && ((((ci & 1u) & (cj >> 1)) | ((cj & 1u) & (ci >> 1))) != 0u);

    unsigned long long balsim = __ballot(msim);
    unsigned long long baldis = __ballot(mdis);
    unsigned long long m      = balsim | baldis;
    if (lane == 0) {
        ns = (float)__popcll(balsim);
        nd = (float)__popcll(baldis);
        wcnt[wave] = (unsigned)__popcll(m);
    }
    __syncthreads();

    // exclusive prefix of wave counts (4 terms, every thread computes)
    unsigned w0 = wcnt[0], w1 = wcnt[1], w2 = wcnt[2], w3 = wcnt[3];
    int total = (int)(w0 + w1 + w2 + w3);
    int wbase = (wave > 0 ? (int)w0 : 0) + (wave > 1 ? (int)w1 : 0)
              + (wave > 2 ? (int)w2 : 0);

    if (msim | mdis) {
        int prefix = __popcll(m & ((1ULL << lane) - 1ULL));
        int pos = wbase + prefix;
        sh_i[pos] = ij.x | (msim ? (int)0x80000000 : 0);
        sh_j[pos] = ij.y;
    }
    __syncthreads();

    // ---- gather phase: 64 groups, paired slots (t, t+64), count≈72 -> 1 pass
    for (int t = g; t < total; t += 128) {
        bool h2 = (t + 64) < total;
        int  tb = h2 ? t + 64 : t;

        int xa_i = sh_i[t],  xa_j = sh_j[t];
        int xb_i = sh_i[tb], xb_j = sh_j[tb];

        const uint4* rai = qfeat + (size_t)(xa_i & 0x7FFFFFFF) * 4;
        const uint4* raj = qfeat + (size_t)xa_j * 4;
        const uint4* rbi = qfeat + (size_t)(xb_i & 0x7FFFFFFF) * 4;
        const uint4* rbj = qfeat + (size_t)xb_j * 4;

        // 4 (or 8 with h2) independent 16B loads in flight per lane
        uint4 A = rai[sub];
        uint4 B = raj[sub];
        uint4 C = rbi[sub];
        uint4 D = rbj[sub];

        float s1 = sq16(A, B);
        float s2 = sq16(C, D);

        s1 += __shfl_xor(s1, 1); s1 += __shfl_xor(s1, 2);
        s2 += __shfl_xor(s2, 1); s2 += __shfl_xor(s2, 2);

        if (sub == 0) {
            accum_edge(s1, ((unsigned)xa_i) >> 31, sim, dis);
            if (h2) accum_edge(s2, ((unsigned)xb_i) >> 31, sim, dis);
        }
    }

    // ---- block reduction (plain store, no global atomics) ----
    #pragma unroll
    for (int off = 32; off > 0; off >>= 1) {
        sim += __shfl_down(sim, off);
        dis += __shfl_down(dis, off);
        ns  += __shfl_down(ns,  off);
        nd  += __shfl_down(nd,  off);
    }
    __shared__ float lds[4][4];
    if (lane == 0) {
        lds[wave][0] = sim; lds[wave][1] = dis;
        lds[wave][2] = ns;  lds[wave][3] = nd;
    }
    __syncthreads();
    if (threadIdx.x == 0) {
        float a = 0.f, b = 0.f, c = 0.f, d4 = 0.f;
        #pragma unroll
        for (int w = 0; w < 4; ++w) {
            a += lds[w][0]; b += lds[w][1]; c += lds[w][2]; d4 += lds[w][3];
        }
        part[blockIdx.x] = make_float4(a, b, c, d4);
    }
}

__global__ void __launch_bounds__(BLOCK)
finalize_kernel(const float4* __restrict__ part,
                float* __restrict__ out) {
    float a = 0.f, b = 0.f, c = 0.f, d4 = 0.f;
    for (int i = threadIdx.x; i < NBLK; i += BLOCK) {
        float4 p = part[i];
        a += p.x; b += p.y; c += p.z; d4 += p.w;
    }
    #pragma unroll
    for (int off = 32; off > 0; off >>= 1) {
        a  += __shfl_down(a,  off);
        b  += __shfl_down(b,  off);
        c  += __shfl_down(c,  off);
        d4 += __shfl_down(d4, off);
    }
    __shared__ float lds[4][4];
    int lane = threadIdx.x & 63;
    int wave = threadIdx.x >> 6;
    if (lane == 0) {
        lds[wave][0] = a; lds[wave][1] = b; lds[wave][2] = c; lds[wave][3] = d4;
    }
    __syncthreads();
    if (threadIdx.x == 0) {
        float sim_sum = 0.f, disim_sum = 0.f, n_sim = 0.f, n_disim = 0.f;
        #pragma unroll
        for (int w = 0; w < 4; ++w) {
            sim_sum   += lds[w][0];
            disim_sum += lds[w][1];
            n_sim     += lds[w][2];
            n_disim   += lds[w][3];
        }
        float total = n_sim + n_disim;
        out[0] = (sim_sum * (n_disim / total) +
                  disim_sum * (n_sim / total)) / total;
    }
}

extern "C" void kernel_launch(void* const* d_in, const int* in_sizes, int n_in,
                              void* d_out, int out_size, void* d_ws, size_t ws_size,
                              hipStream_t stream) {
    const int*   edges  = (const int*)d_in[0];    // (N_EDGES, 2) int32
    const float* probas = (const float*)d_in[1];  // (N_NODES,)
    const float* feats  = (const float*)d_in[2];  // (N_NODES, 64) fp32

    float4*   part = (float4*)d_ws;
    unsigned* cls  = (unsigned*)((char*)d_ws + CLS_OFF);
    unsigned* qf   = (unsigned*)((char*)d_ws + QF_OFF);

    const int NF4 = N_NODES * 16;
    prep_kernel<<<(NF4 + BLOCK - 1) / BLOCK, BLOCK, 0, stream>>>(
        probas, (const float4*)feats, cls, qf);

    edge_loss_kernel<<<NBLK, BLOCK, 0, stream>>>(
        (const int2*)edges, cls, (const uint4*)qf, part);

    finalize_kernel<<<1, BLOCK, 0, stream>>>(part, (float*)d_out);
}